// Round 9
// baseline (286.012 us; speedup 1.0000x reference)
//
#include <hip/hip_runtime.h>
#include <hip/hip_bf16.h>

// TensorTrainLMN: out[b, a*128+h] = X[b,:] @ W[:, a*128+h] + bias
//   X[b] = [nh[b,0,:128], ..., nh[b,15,:128], te[b,:128]]   (K = 2176)
// tt_fold: folds A@B^(15-c)@U_out (exact f32) into W bf16, PRE-PACKED in MFMA
//   B-fragment order: Wp[kt][slot=k8][n 0..511][8 bf16]. (verified r5-r8)
// tt_gemm: A staged f32 -> LDS via global_load_lds, 4-slot ring, DISTANCE-3
//   prefetch with hand-counted vmcnt (no register consumer -> no HBM-latency
//   stall). f32->bf16 conversion at READ side (cvt_pk). Source-side XOR
//   swizzle (k16 ^= row&15) kills the stride-256B bank conflict; same
//   involution applied on read. B-frags: global->VGPR from L2-resident Wp,
//   distance-1 reg double buffer (compiler-counted waits).

typedef short bf16x8 __attribute__((ext_vector_type(8)));
typedef float f32x4  __attribute__((ext_vector_type(4)));

__device__ __forceinline__ unsigned f2bfbits(float f) {
    unsigned u = __builtin_bit_cast(unsigned, f);
    return (u + 0x7FFFu + ((u >> 16) & 1u)) >> 16;   // round-to-nearest-even
}
// compiler fuses pairs into v_cvt_pk_bf16_f32 (m240)
__device__ __forceinline__ unsigned pack2(float a, float b) {
    unsigned lo = (unsigned)__builtin_bit_cast(unsigned short, __float2bfloat16(a));
    unsigned hi = (unsigned)__builtin_bit_cast(unsigned short, __float2bfloat16(b));
    return lo | (hi << 16);
}

// ---------------------------------------------------------------------------
// Fold kernel: 72 blocks x 512 threads (verified r7/r8).
// ---------------------------------------------------------------------------
#define FS 68   // fold matmul LDS row stride (floats); 16B-aligned, 2-way banks

__global__ __launch_bounds__(512) void tt_fold(
    const float* __restrict__ Ag,    // (4,128,64)
    const float* __restrict__ Bg,    // (4,64,64)
    const float* __restrict__ Abg,   // (4,1,64)
    const float* __restrict__ Utg,   // (4,128,64)
    const float* __restrict__ btg,   // (4,1,64)
    const float* __restrict__ Uog,   // (4,64,128)
    const float* __restrict__ bog,   // (4,1,128)
    unsigned short* __restrict__ Wp, // [34][8][512][8] bf16
    float* __restrict__ biasOut)     // [512]
{
    __shared__ __align__(16) float L[23552];   // 92 KB
    const int t = threadIdx.x;
    const int bid = blockIdx.x;

    auto mm = [&](float* d, const float* x, const float* y, const float* add) {
        const int r = t >> 3, c0 = (t & 7) << 3;
        float acc[8];
#pragma unroll
        for (int j = 0; j < 8; ++j) acc[j] = 0.f;
        for (int k = 0; k < 64; ++k) {
            const float a = x[r * FS + k];
            const float4 y0 = *(const float4*)(y + k * FS + c0);
            const float4 y1 = *(const float4*)(y + k * FS + c0 + 4);
            acc[0] += a * y0.x; acc[1] += a * y0.y;
            acc[2] += a * y0.z; acc[3] += a * y0.w;
            acc[4] += a * y1.x; acc[5] += a * y1.y;
            acc[6] += a * y1.z; acc[7] += a * y1.w;
        }
        if (add) {
#pragma unroll
            for (int j = 0; j < 8; ++j) acc[j] += add[r * FS + c0 + j];
        }
#pragma unroll
        for (int j = 0; j < 8; ++j) d[r * FS + c0 + j] = acc[j];
    };

    float* buf[4];
    buf[0] = L;
    buf[1] = L + 4352;
    buf[2] = L + 8704;
    buf[3] = L + 13056;
    float* const Pbuf = L + 17408;   // 64x64 dense (stride 64)
    float* const UC   = L + 21504;   // 16x128 staging

    if (bid < 68) {
        int a, p, kbase;
        const float* src;
        if (bid < 64) { a = bid >> 4; const int c = bid & 15; p = 15 - c; kbase = c * 128; src = Ag  + a * 8192; }
        else          { a = bid - 64; p = 16; kbase = 2048;               src = Utg + a * 8192; }
        const float* Bmat = Bg + a * 4096;

        for (int i = t; i < 4096; i += 512) {
            const int row = i >> 6, col = i & 63;
            buf[0][row * FS + col] = Bmat[i];
            buf[2][row * FS + col] = (row == col) ? 1.f : 0.f;
        }
        __syncthreads();
        int bcur = 0, rcur = 2;
        int e = p;
        while (e) {
            if (e & 1) { mm(buf[rcur ^ 1], buf[rcur], buf[bcur], nullptr); rcur ^= 1; __syncthreads(); }
            e >>= 1;
            if (e)     { mm(buf[bcur ^ 1], buf[bcur], buf[bcur], nullptr); bcur ^= 1; __syncthreads(); }
        }

        {
            const int prow = t >> 3, pc0 = (t & 7) << 3;
#pragma unroll
            for (int j = 0; j < 8; ++j)
                Pbuf[prow * 64 + pc0 + j] = buf[rcur][prow * FS + pc0 + j];
        }
        __syncthreads();

        // M1 = src(128x64) @ P, stored stride-65 at L (bufs dead now)
        float* M1 = L;
        {
            const int i = t >> 2, r0 = (t & 3) << 4;
            float acc[16];
#pragma unroll
            for (int j = 0; j < 16; ++j) acc[j] = 0.f;
            for (int q = 0; q < 64; ++q) {
                const float av = src[i * 64 + q];
                const float4* pr = (const float4*)(Pbuf + q * 64 + r0);
#pragma unroll
                for (int jj = 0; jj < 4; ++jj) {
                    float4 v = pr[jj];
                    acc[4 * jj + 0] += av * v.x;
                    acc[4 * jj + 1] += av * v.y;
                    acc[4 * jj + 2] += av * v.z;
                    acc[4 * jj + 3] += av * v.w;
                }
            }
#pragma unroll
            for (int j = 0; j < 16; ++j) M1[i * 65 + r0 + j] = acc[j];
        }
        __syncthreads();

        // W2 = M1(128x64) @ Uo(64x128); Uo staged 16 rows/chunk
        const float* UoA = Uog + a * 8192;
        const int i = t >> 2, h0 = (t & 3) << 5;
        float acc2[32];
#pragma unroll
        for (int j = 0; j < 32; ++j) acc2[j] = 0.f;
        for (int ch = 0; ch < 4; ++ch) {
            __syncthreads();
            for (int idx = t; idx < 2048; idx += 512) UC[idx] = UoA[ch * 2048 + idx];
            __syncthreads();
            for (int rr = 0; rr < 16; ++rr) {
                const float m = M1[i * 65 + ch * 16 + rr];
                const float4* ur = (const float4*)(UC + rr * 128 + h0);
#pragma unroll
                for (int jj = 0; jj < 8; ++jj) {
                    float4 v = ur[jj];
                    acc2[4 * jj + 0] += m * v.x;
                    acc2[4 * jj + 1] += m * v.y;
                    acc2[4 * jj + 2] += m * v.z;
                    acc2[4 * jj + 3] += m * v.w;
                }
            }
        }
        {
            const int k = kbase + i;
            const int kt = k >> 6, slot = (k >> 3) & 7, widx = k & 7;
#pragma unroll
            for (int j = 0; j < 32; ++j) {
                const int n = a * 128 + h0 + j;
                Wp[((size_t)(kt * 8 + slot) * 512 + n) * 8 + widx] =
                    (unsigned short)f2bfbits(acc2[j]);
            }
        }
    } else {
        // bias: S16 = sum_{p<16} B^p, B16 = B^16
        const int a = bid - 68;
        const float* Bmat = Bg + a * 4096;
        for (int i = t; i < 4096; i += 512) {
            const int row = i >> 6, col = i & 63;
            buf[0][row * FS + col] = Bmat[i];
            buf[2][row * FS + col] = (row == col) ? 1.f : 0.f;
        }
        __syncthreads();
        int bcur = 0, scur = 2;
        for (int rnd = 0; rnd < 4; ++rnd) {
            mm(buf[scur ^ 1], buf[bcur], buf[scur], buf[scur]);
            mm(buf[bcur ^ 1], buf[bcur], buf[bcur], nullptr);
            __syncthreads();
            scur ^= 1; bcur ^= 1;
        }
        float* vv = Pbuf;
        if (t < 64) {
            float acc = 0.f;
            const float* S16 = buf[scur];
            const float* B16 = buf[bcur];
            for (int q = 0; q < 64; ++q)
                acc += Abg[a * 64 + q] * S16[q * FS + t]
                     + btg[a * 64 + q] * B16[q * FS + t];
            vv[t] = acc;
        }
        __syncthreads();
        if (t < 128) {
            float accb = bog[a * 128 + t];
            const float* UoA = Uog + a * 8192;
            for (int r = 0; r < 64; ++r) accb += vv[r] * UoA[r * 128 + t];
            biasOut[a * 128 + t] = accb;
        }
    }
}
#undef FS

// ---------------------------------------------------------------------------
// Main GEMM: 1024 blocks x 256 threads (4 waves), block 64M x 256N,
// wave 64x64, BK=64 (34 K-tiles).
// A: f32 in LDS, 4-slot ring (4x16KB), global_load_lds width 16, distance-3,
//    hand-counted vmcnt; XOR swizzle (k16 ^= row&15) on SOURCE + READ.
// B: reg double-buffer from L2-resident Wp (distance-1, compiler waits).
// Per iter: [LOADB(i+1); vmcnt(N); barrier; GA(i+3); compute(i)].
// ---------------------------------------------------------------------------
__global__ __launch_bounds__(256) void tt_gemm(
    const float* __restrict__ nh,           // (32768,16,128)
    const float* __restrict__ te,           // (32768,128)
    const unsigned short* __restrict__ Wp,  // [34][8][512][8] bf16
    const float* __restrict__ bias,         // [512]
    float* __restrict__ out)                // (32768,512)
{
    __shared__ __align__(16) char Ab[65536];   // 4 slots x [row 0..63][16 x 16B]

    const int t = threadIdx.x;
    const int lane = t & 63, w = t >> 6;
    // chunked XCD map: the two n-halves of one m-tile land on the same XCD.
    const int lt = (blockIdx.x & 7) * 128 + (blockIdx.x >> 3);  // 1024 = 8*128
    const int m0 = (lt >> 1) * 64;
    const int wc = (lt & 1) * 4 + w;             // n-col group 0..7
    const int lx = lane & 15, lg = lane >> 4;

    // --- A staging geometry (global_load_lds): wave w, op j stages rows
    //     16w+4j .. +3; lane: row_local = lane>>4, k16-slot = lane&15.
    //     Source pre-swizzled: k16 = (lane&15) ^ (row&15).
    const int rowb = 16 * w + (lane >> 4);       // absolute row base (j=0)
    int sw4[4];
#pragma unroll
    for (int j = 0; j < 4; ++j)
        sw4[j] = ((lane & 15) ^ ((lane >> 4) + 4 * j)) * 4;   // float offset

    // --- A frag read offsets: byte = slot*16384 + (fm*16+lx)*256
    //     + (((kk<<3)|(lg<<1)|h) ^ lx) * 16
    int uoff[2][2];
#pragma unroll
    for (int kk = 0; kk < 2; ++kk)
#pragma unroll
        for (int h = 0; h < 2; ++h)
            uoff[kk][h] = ((((kk << 3) | (lg << 1) | h) ^ lx) << 4);
    const int arow = lx * 256;

    // B frag byte base: + kt*65536 + kk*32768 + fn*256
    const char* const wbase = (const char*)Wp + lg * 8192 + wc * 1024 + lx * 16;

    f32x4 acc[4][4] = {};
    uint4  bF0[4][2], bF1[4][2];   // B frags (distance-1 double buffer)

#define SB() __builtin_amdgcn_sched_barrier(0)

#define GA(slot_, kt_) do {                                                    \
    const int _kt = (kt_);                                                     \
    char* _ldb = Ab + (slot_) * 16384 + (w * 4) * 1024;                        \
    _Pragma("unroll")                                                          \
    for (int _j = 0; _j < 4; ++_j) {                                           \
        const float* _src;                                                     \
        if (_kt < 32) _src = nh + (size_t)(m0 + rowb + 4 * _j) * 2048 + _kt * 64 + sw4[_j]; \
        else          _src = te + (size_t)(m0 + rowb + 4 * _j) * 128 + (_kt - 32) * 64 + sw4[_j]; \
        __builtin_amdgcn_global_load_lds(                                      \
            (const __attribute__((address_space(1))) unsigned int*)_src,       \
            (__attribute__((address_space(3))) unsigned int*)(_ldb + _j * 1024),\
            16, 0, 0);                                                         \
    }                                                                          \
} while (0)

#define LOADB(dst, kt_) do {                                                   \
    const char* _q = wbase + (size_t)(kt_) * 65536;                            \
    _Pragma("unroll")                                                          \
    for (int _kk = 0; _kk < 2; ++_kk)                                          \
        _Pragma("unroll")                                                      \
        for (int _fn = 0; _fn < 4; ++_fn)                                      \
            dst[_fn][_kk] = *(const uint4*)(_q + _kk * 32768 + _fn * 256);     \
} while (0)

#define COMPUTE(slotbase, bsrc) do {                                           \
    _Pragma("unroll")                                                          \
    for (int _kk = 0; _kk < 2; ++_kk) {                                        \
        bf16x8 _aF[4];                                                         \
        _Pragma("unroll")                                                      \
        for (int _fm = 0; _fm < 4; ++_fm) {                                    \
            const char* _b = Ab + (slotbase) + _fm * 4096 + arow;              \
            float4 _lo = *(const float4*)(_b + uoff[_kk][0]);                  \
            float4 _hi = *(const float4*)(_b + uoff[_kk][1]);                  \
            uint4 _u;                                                          \
            _u.x = pack2(_lo.x, _lo.y);  _u.y = pack2(_lo.z, _lo.w);           \
            _u.z = pack2(_hi.x, _hi.y);  _u.w = pack2(_hi.z, _hi.w);           \
            _aF[_fm] = __builtin_bit_cast(bf16x8, _u);                         \
        }                                                                      \
        _Pragma("unroll")                                                      \
        for (int _fm = 0; _fm < 4; ++_fm)                                      \
            _Pragma("unroll")                                                  \
            for (int _fn = 0; _fn < 4; ++_fn)                                  \
                acc[_fm][_fn] = __builtin_amdgcn_mfma_f32_16x16x32_bf16(       \
                    _aF[_fm], __builtin_bit_cast(bf16x8, bsrc[_fn][_kk]),      \
                    acc[_fm][_fn], 0, 0, 0);                                   \
    }                                                                          \
} while (0)

// One pipeline step. N_ = exact outstanding-op count allowed at the wait
// (ops issued after tile kt_'s GA group); GA after barrier: the slot it
// overwrites (tile kt_-1's) is dead once all waves passed this barrier.
#define STEP(kt_, NSTR, DO_GA, DO_B, BCUR, BNXT) do {                          \
    if (DO_B) LOADB(BNXT, (kt_) + 1);                                          \
    asm volatile("s_waitcnt vmcnt(" NSTR ")" ::: "memory");                    \
    __builtin_amdgcn_s_barrier();                                              \
    SB();                                                                      \
    if (DO_GA) { GA(((kt_) + 3) & 3, (kt_) + 3); SB(); }                       \
    COMPUTE(((kt_) & 3) * 16384, BCUR);                                        \
} while (0)

    // prologue: slots 0..2 staged (pinned order for exact vmcnt counts)
    GA(0, 0); SB();
    GA(1, 1); SB();
    GA(2, 2); SB();
    LOADB(bF0, 0);

    STEP(0, "24", 1, 1, bF0, bF1);
    STEP(1, "32", 1, 1, bF1, bF0);
    STEP(2, "40", 1, 1, bF0, bF1);
#pragma unroll 1
    for (int kt = 3; kt < 31; kt += 2) {
        STEP(kt,     "32", 1, 1, bF1, bF0);
        STEP(kt + 1, "32", 1, 1, bF0, bF1);
    }
    STEP(31, "32", 0, 1, bF1, bF0);
    STEP(32, "28", 0, 1, bF0, bF1);
    STEP(33, "16", 0, 0, bF1, bF0);

#undef STEP
#undef COMPUTE
#undef LOADB
#undef GA
#undef SB

    // epilogue: C/D layout col = lane&15, row = (lane>>4)*4 + reg  [m89]
    const int orow = m0 + lg * 4;
    const int ocol = wc * 64 + lx;
    float bv[4];
#pragma unroll
    for (int fn = 0; fn < 4; ++fn) bv[fn] = bias[ocol + fn * 16];
#pragma unroll
    for (int fm = 0; fm < 4; ++fm)
#pragma unroll
        for (int fn = 0; fn < 4; ++fn)
#pragma unroll
            for (int j = 0; j < 4; ++j)
                out[(size_t)(orow + fm * 16 + j) * 512 + ocol + fn * 16] =
                    acc[fm][fn][j] + bv[fn];
}

// ---------------------------------------------------------------------------
extern "C" void kernel_launch(void* const* d_in, const int* in_sizes, int n_in,
                              void* d_out, int out_size, void* d_ws, size_t ws_size,
                              hipStream_t stream) {
    const float* nh  = (const float*)d_in[0];
    const float* te  = (const float*)d_in[1];
    const float* Ag  = (const float*)d_in[2];
    const float* Bg  = (const float*)d_in[3];
    const float* Abg = (const float*)d_in[4];
    const float* Utg = (const float*)d_in[5];
    const float* btg = (const float*)d_in[6];
    const float* Uog = (const float*)d_in[7];
    const float* bog = (const float*)d_in[8];

    unsigned short* Wp = (unsigned short*)d_ws;              // 34*8*512*8*2 B
    float* bias = (float*)((char*)d_ws + (size_t)34 * 8 * 512 * 8 * 2);
    float* out = (float*)d_out;

    hipLaunchKernelGGL(tt_fold, dim3(72), dim3(512), 0, stream,
                       Ag, Bg, Abg, Utg, btg, Uog, bog, Wp, bias);
    hipLaunchKernelGGL(tt_gemm, dim3(1024), dim3(256), 0, stream,
                       nh, te, Wp, bias, out);
}

// Round 10
// 201.230 us; speedup vs baseline: 1.4213x; 1.4213x over previous
//
#include <hip/hip_runtime.h>
#include <hip/hip_bf16.h>

// TensorTrainLMN: out[b, a*128+h] = X[b,:] @ W[:, a*128+h] + bias
//   X[b] = [nh[b,0,:128], ..., nh[b,15,:128], te[b,:128]]   (K = 2176)
// tt_fold: folds A@B^(15-c)@U_out (exact f32) into W bf16, PRE-PACKED in MFMA
//   B-fragment order: Wp[kt][slot=k8][n 0..511][8 bf16]. (verified r5-r9)
// tt_gemm: r8 structure (A reg-staged -> 16KB LDS dbuf, B reg double-buffer
//   from L2-resident Wp, SYNC_NODRAIN barriers) with the pipeline re-timed to
//   DISTANCE-2 on both streams at constant register count:
//     iter k: WRITEA(va[(k+1)&1], tile k+1, loaded at k-2)
//             LOADA(same regs, tile k+3)          (WAR enforces order)
//             COMPUTE(buf k&1, bF[k&1], tile k, loaded at k-2)
//             LOADB(bF[k&1], tile k+2)
//   Equilibrium iter time ~ HBM-latency/distance -> expect ~2x vs r8.

typedef short bf16x8 __attribute__((ext_vector_type(8)));
typedef float f32x4  __attribute__((ext_vector_type(4)));

__device__ __forceinline__ unsigned f2bfbits(float f) {
    unsigned u = __builtin_bit_cast(unsigned, f);
    return (u + 0x7FFFu + ((u >> 16) & 1u)) >> 16;   // round-to-nearest-even
}
// compiler fuses pairs into v_cvt_pk_bf16_f32 (m240)
__device__ __forceinline__ unsigned pack2(float a, float b) {
    unsigned lo = (unsigned)__builtin_bit_cast(unsigned short, __float2bfloat16(a));
    unsigned hi = (unsigned)__builtin_bit_cast(unsigned short, __float2bfloat16(b));
    return lo | (hi << 16);
}

// publish LDS writes, cross barrier WITHOUT draining vmem prefetches
#define SYNC_NODRAIN() do {                                   \
    asm volatile("s_waitcnt lgkmcnt(0)" ::: "memory");        \
    __builtin_amdgcn_s_barrier();                             \
} while (0)

// ---------------------------------------------------------------------------
// Fold kernel: 72 blocks x 512 threads (verified r7-r9).
// ---------------------------------------------------------------------------
#define FS 68   // fold matmul LDS row stride (floats); 16B-aligned, 2-way banks

__global__ __launch_bounds__(512) void tt_fold(
    const float* __restrict__ Ag,    // (4,128,64)
    const float* __restrict__ Bg,    // (4,64,64)
    const float* __restrict__ Abg,   // (4,1,64)
    const float* __restrict__ Utg,   // (4,128,64)
    const float* __restrict__ btg,   // (4,1,64)
    const float* __restrict__ Uog,   // (4,64,128)
    const float* __restrict__ bog,   // (4,1,128)
    unsigned short* __restrict__ Wp, // [34][8][512][8] bf16
    float* __restrict__ biasOut)     // [512]
{
    __shared__ __align__(16) float L[23552];   // 92 KB
    const int t = threadIdx.x;
    const int bid = blockIdx.x;

    auto mm = [&](float* d, const float* x, const float* y, const float* add) {
        const int r = t >> 3, c0 = (t & 7) << 3;
        float acc[8];
#pragma unroll
        for (int j = 0; j < 8; ++j) acc[j] = 0.f;
        for (int k = 0; k < 64; ++k) {
            const float a = x[r * FS + k];
            const float4 y0 = *(const float4*)(y + k * FS + c0);
            const float4 y1 = *(const float4*)(y + k * FS + c0 + 4);
            acc[0] += a * y0.x; acc[1] += a * y0.y;
            acc[2] += a * y0.z; acc[3] += a * y0.w;
            acc[4] += a * y1.x; acc[5] += a * y1.y;
            acc[6] += a * y1.z; acc[7] += a * y1.w;
        }
        if (add) {
#pragma unroll
            for (int j = 0; j < 8; ++j) acc[j] += add[r * FS + c0 + j];
        }
#pragma unroll
        for (int j = 0; j < 8; ++j) d[r * FS + c0 + j] = acc[j];
    };

    float* buf[4];
    buf[0] = L;
    buf[1] = L + 4352;
    buf[2] = L + 8704;
    buf[3] = L + 13056;
    float* const Pbuf = L + 17408;   // 64x64 dense (stride 64)
    float* const UC   = L + 21504;   // 16x128 staging

    if (bid < 68) {
        int a, p, kbase;
        const float* src;
        if (bid < 64) { a = bid >> 4; const int c = bid & 15; p = 15 - c; kbase = c * 128; src = Ag  + a * 8192; }
        else          { a = bid - 64; p = 16; kbase = 2048;               src = Utg + a * 8192; }
        const float* Bmat = Bg + a * 4096;

        for (int i = t; i < 4096; i += 512) {
            const int row = i >> 6, col = i & 63;
            buf[0][row * FS + col] = Bmat[i];
            buf[2][row * FS + col] = (row == col) ? 1.f : 0.f;
        }
        __syncthreads();
        int bcur = 0, rcur = 2;
        int e = p;
        while (e) {
            if (e & 1) { mm(buf[rcur ^ 1], buf[rcur], buf[bcur], nullptr); rcur ^= 1; __syncthreads(); }
            e >>= 1;
            if (e)     { mm(buf[bcur ^ 1], buf[bcur], buf[bcur], nullptr); bcur ^= 1; __syncthreads(); }
        }

        {
            const int prow = t >> 3, pc0 = (t & 7) << 3;
#pragma unroll
            for (int j = 0; j < 8; ++j)
                Pbuf[prow * 64 + pc0 + j] = buf[rcur][prow * FS + pc0 + j];
        }
        __syncthreads();

        // M1 = src(128x64) @ P, stored stride-65 at L (bufs dead now)
        float* M1 = L;
        {
            const int i = t >> 2, r0 = (t & 3) << 4;
            float acc[16];
#pragma unroll
            for (int j = 0; j < 16; ++j) acc[j] = 0.f;
            for (int q = 0; q < 64; ++q) {
                const float av = src[i * 64 + q];
                const float4* pr = (const float4*)(Pbuf + q * 64 + r0);
#pragma unroll
                for (int jj = 0; jj < 4; ++jj) {
                    float4 v = pr[jj];
                    acc[4 * jj + 0] += av * v.x;
                    acc[4 * jj + 1] += av * v.y;
                    acc[4 * jj + 2] += av * v.z;
                    acc[4 * jj + 3] += av * v.w;
                }
            }
#pragma unroll
            for (int j = 0; j < 16; ++j) M1[i * 65 + r0 + j] = acc[j];
        }
        __syncthreads();

        // W2 = M1(128x64) @ Uo(64x128); Uo staged 16 rows/chunk
        const float* UoA = Uog + a * 8192;
        const int i = t >> 2, h0 = (t & 3) << 5;
        float acc2[32];
#pragma unroll
        for (int j = 0; j < 32; ++j) acc2[j] = 0.f;
        for (int ch = 0; ch < 4; ++ch) {
            __syncthreads();
            for (int idx = t; idx < 2048; idx += 512) UC[idx] = UoA[ch * 2048 + idx];
            __syncthreads();
            for (int rr = 0; rr < 16; ++rr) {
                const float m = M1[i * 65 + ch * 16 + rr];
                const float4* ur = (const float4*)(UC + rr * 128 + h0);
#pragma unroll
                for (int jj = 0; jj < 8; ++jj) {
                    float4 v = ur[jj];
                    acc2[4 * jj + 0] += m * v.x;
                    acc2[4 * jj + 1] += m * v.y;
                    acc2[4 * jj + 2] += m * v.z;
                    acc2[4 * jj + 3] += m * v.w;
                }
            }
        }
        {
            const int k = kbase + i;
            const int kt = k >> 6, slot = (k >> 3) & 7, widx = k & 7;
#pragma unroll
            for (int j = 0; j < 32; ++j) {
                const int n = a * 128 + h0 + j;
                Wp[((size_t)(kt * 8 + slot) * 512 + n) * 8 + widx] =
                    (unsigned short)f2bfbits(acc2[j]);
            }
        }
    } else {
        // bias: S16 = sum_{p<16} B^p, B16 = B^16
        const int a = bid - 68;
        const float* Bmat = Bg + a * 4096;
        for (int i = t; i < 4096; i += 512) {
            const int row = i >> 6, col = i & 63;
            buf[0][row * FS + col] = Bmat[i];
            buf[2][row * FS + col] = (row == col) ? 1.f : 0.f;
        }
        __syncthreads();
        int bcur = 0, scur = 2;
        for (int rnd = 0; rnd < 4; ++rnd) {
            mm(buf[scur ^ 1], buf[bcur], buf[scur], buf[scur]);
            mm(buf[bcur ^ 1], buf[bcur], buf[bcur], nullptr);
            __syncthreads();
            scur ^= 1; bcur ^= 1;
        }
        float* vv = Pbuf;
        if (t < 64) {
            float acc = 0.f;
            const float* S16 = buf[scur];
            const float* B16 = buf[bcur];
            for (int q = 0; q < 64; ++q)
                acc += Abg[a * 64 + q] * S16[q * FS + t]
                     + btg[a * 64 + q] * B16[q * FS + t];
            vv[t] = acc;
        }
        __syncthreads();
        if (t < 128) {
            float accb = bog[a * 128 + t];
            const float* UoA = Uog + a * 8192;
            for (int r = 0; r < 64; ++r) accb += vv[r] * UoA[r * 128 + t];
            biasOut[a * 128 + t] = accb;
        }
    }
}
#undef FS

// ---------------------------------------------------------------------------
// Main GEMM: 1024 blocks x 256 threads (4 waves), block 64M x 256N,
// wave 64x64, BK=64 (34 K-tiles). A-only LDS (2 x 8KB). DISTANCE-2 pipeline
// on both streams at r8's register footprint. SYNC_NODRAIN barriers.
// ---------------------------------------------------------------------------
__global__ __launch_bounds__(256) void tt_gemm(
    const float* __restrict__ nh,           // (32768,16,128)
    const float* __restrict__ te,           // (32768,128)
    const unsigned short* __restrict__ Wp,  // [34][8][512][8] bf16
    const float* __restrict__ bias,         // [512]
    float* __restrict__ out)                // (32768,512)
{
    __shared__ __align__(16) char Ab[16384];   // [d][kk][lg][row 0..63][16B]

    const int t = threadIdx.x;
    const int lane = t & 63, wave = t >> 6;
    // chunked XCD map: the two n-halves of one m-tile land on the same XCD.
    const int lt = (blockIdx.x & 7) * 128 + (blockIdx.x >> 3);  // 1024 = 8*128
    const int m0 = (lt >> 1) * 64;
    const int wc = (lt & 1) * 4 + wave;          // n-col group 0..7
    const int lx = lane & 15, lg = lane >> 4;

    // A staging: thread -> row r (0..63), k-chunk c (16 f32)
    const int r = t >> 2, c = t & 3;
    const float* nhp = nh + (size_t)(m0 + r) * 2048 + c * 16;
    const float* tep = te + (size_t)(m0 + r) * 128  + c * 16;
    const int awoff = (c >> 1) * 4096 + (c & 1) * 2048 + r * 16;
    const int aroff = lg * 1024 + lx * 16;       // + d*8192 + kk*4096 + fm*256

    // B frag byte base: + kt*65536 + kk*32768 + fn*256
    const char* const wbase = (const char*)Wp + lg * 8192 + wc * 1024 + lx * 16;

    f32x4 acc[4][4] = {};
    float4 va0[4], va1[4];        // A staging (distance-2: load k -> write k+2)
    uint4  bF0[4][2], bF1[4][2];  // B frags (distance-2 double buffer)

#define LOADA(dst, kt_) do {                                                   \
    const float* _p = ((kt_) < 32) ? (nhp + (kt_) * 64) : (tep + ((kt_) - 32) * 64); \
    _Pragma("unroll")                                                          \
    for (int _j = 0; _j < 4; ++_j) dst[_j] = *(const float4*)(_p + 4 * _j);    \
} while (0)

#define WRITEA(src, d_) do {                                                   \
    uint4 _w0, _w1;                                                            \
    _w0.x = pack2(src[0].x, src[0].y);  _w0.y = pack2(src[0].z, src[0].w);     \
    _w0.z = pack2(src[1].x, src[1].y);  _w0.w = pack2(src[1].z, src[1].w);     \
    _w1.x = pack2(src[2].x, src[2].y);  _w1.y = pack2(src[2].z, src[2].w);     \
    _w1.z = pack2(src[3].x, src[3].y);  _w1.w = pack2(src[3].z, src[3].w);     \
    *(uint4*)(Ab + (d_) * 8192 + awoff)        = _w0;                          \
    *(uint4*)(Ab + (d_) * 8192 + awoff + 1024) = _w1;                          \
} while (0)

#define LOADB(dst, kt_) do {                                                   \
    const char* _q = wbase + (size_t)(kt_) * 65536;                            \
    _Pragma("unroll")                                                          \
    for (int _kk = 0; _kk < 2; ++_kk)                                          \
        _Pragma("unroll")                                                      \
        for (int _fn = 0; _fn < 4; ++_fn)                                      \
            dst[_fn][_kk] = *(const uint4*)(_q + _kk * 32768 + _fn * 256);     \
} while (0)

#define COMPUTE(d_, bsrc) do {                                                 \
    _Pragma("unroll")                                                          \
    for (int _kk = 0; _kk < 2; ++_kk) {                                        \
        bf16x8 _aF[4];                                                         \
        _Pragma("unroll")                                                      \
        for (int _fm = 0; _fm < 4; ++_fm)                                      \
            _aF[_fm] = *(const bf16x8*)(Ab + (d_) * 8192 + _kk * 4096 + aroff + _fm * 256); \
        _Pragma("unroll")                                                      \
        for (int _fm = 0; _fm < 4; ++_fm)                                      \
            _Pragma("unroll")                                                  \
            for (int _fn = 0; _fn < 4; ++_fn)                                  \
                acc[_fm][_fn] = __builtin_amdgcn_mfma_f32_16x16x32_bf16(       \
                    _aF[_fm], __builtin_bit_cast(bf16x8, bsrc[_fn][_kk]),      \
                    acc[_fm][_fn], 0, 0, 0);                                   \
    }                                                                          \
} while (0)

    // prologue: buf0 <- tile0; va1 <- tile1 (written iter 0); va0 <- tile2
    // (written iter 1); bF0 <- tile0; bF1 <- tile1.
    LOADA(va0, 0);
    WRITEA(va0, 0);
    LOADA(va1, 1);
    LOADA(va0, 2);
    LOADB(bF0, 0);
    LOADB(bF1, 1);
    SYNC_NODRAIN();

#pragma unroll 1
    for (int kt = 0; kt < 34; kt += 2) {
        // ---- even k: write tile k+1 (va1, loaded k-2); compute tile k ----
        WRITEA(va1, 1);                         // waits va1: 2-iter distance
        if (kt + 3 < 34) LOADA(va1, kt + 3);    // reload same regs (WAR-ordered)
        COMPUTE(0, bF0);                        // bF0 = tile k, loaded k-2
        if (kt + 2 < 34) LOADB(bF0, kt + 2);
        SYNC_NODRAIN();

        // ---- odd k+1: write tile k+2 (va0, loaded k-1); compute tile k+1 ----
        if (kt + 2 < 34) {
            WRITEA(va0, 0);
            if (kt + 4 < 34) LOADA(va0, kt + 4);
        }
        COMPUTE(1, bF1);                        // bF1 = tile k+1, loaded k-1
        if (kt + 3 < 34) LOADB(bF1, kt + 3);
        SYNC_NODRAIN();
    }
#undef LOADA
#undef WRITEA
#undef LOADB
#undef COMPUTE

    // epilogue: C/D layout col = lane&15, row = (lane>>4)*4 + reg  [m89]
    const int orow = m0 + lg * 4;
    const int ocol = wc * 64 + lx;
    float bv[4];
#pragma unroll
    for (int fn = 0; fn < 4; ++fn) bv[fn] = bias[ocol + fn * 16];
#pragma unroll
    for (int fm = 0; fm < 4; ++fm)
#pragma unroll
        for (int fn = 0; fn < 4; ++fn)
#pragma unroll
            for (int j = 0; j < 4; ++j)
                out[(size_t)(orow + fm * 16 + j) * 512 + ocol + fn * 16] =
                    acc[fm][fn][j] + bv[fn];
}

// ---------------------------------------------------------------------------
extern "C" void kernel_launch(void* const* d_in, const int* in_sizes, int n_in,
                              void* d_out, int out_size, void* d_ws, size_t ws_size,
                              hipStream_t stream) {
    const float* nh  = (const float*)d_in[0];
    const float* te  = (const float*)d_in[1];
    const float* Ag  = (const float*)d_in[2];
    const float* Bg  = (const float*)d_in[3];
    const float* Abg = (const float*)d_in[4];
    const float* Utg = (const float*)d_in[5];
    const float* btg = (const float*)d_in[6];
    const float* Uog = (const float*)d_in[7];
    const float* bog = (const float*)d_in[8];

    unsigned short* Wp = (unsigned short*)d_ws;              // 34*8*512*8*2 B
    float* bias = (float*)((char*)d_ws + (size_t)34 * 8 * 512 * 8 * 2);
    float* out = (float*)d_out;

    hipLaunchKernelGGL(tt_fold, dim3(72), dim3(512), 0, stream,
                       Ag, Bg, Abg, Utg, btg, Uog, bog, Wp, bias);
    hipLaunchKernelGGL(tt_gemm, dim3(1024), dim3(256), 0, stream,
                       nh, te, Wp, bias, out);
}